// Round 1
// baseline (543.538 us; speedup 1.0000x reference)
//
#include <hip/hip_runtime.h>
#include <hip/hip_bf16.h>

typedef __bf16 bf16;
typedef __attribute__((ext_vector_type(4))) __bf16 bf16x4;
typedef __attribute__((ext_vector_type(8))) __bf16 bf16x8;
typedef __attribute__((ext_vector_type(4))) float floatx4;

#define BB 16
#define NN 576
#define CC 768
#define HH 12
#define DH 64

// async global->LDS, 16B per lane; LDS dest = wave-uniform base + lane*16
#define GLOAD_LDS16(gp, lp) __builtin_amdgcn_global_load_lds( \
    (const __attribute__((address_space(1))) unsigned int*)(const void*)(gp), \
    (__attribute__((address_space(3))) unsigned int*)(void*)(lp), 16, 0, 0)

// ---------------- convert fp32 -> bf16 (vectorized x4) ----------------
__global__ void k_convert(const float* __restrict__ in, bf16* __restrict__ out, int n4){
  int i = blockIdx.x*blockDim.x + threadIdx.x;
  if (i < n4){
    float4 f = ((const float4*)in)[i];
    bf16x4 o;
    o[0]=(bf16)f.x; o[1]=(bf16)f.y; o[2]=(bf16)f.z; o[3]=(bf16)f.w;
    ((bf16x4*)out)[i] = o;
  }
}

// ---------------- tiled transpose fp32[R][Cc] -> bf16[Cc][R] ----------------
__global__ void k_transpose(const float* __restrict__ src, bf16* __restrict__ dst, int R, int Cc){
  __shared__ float tile[32][33];
  int c0 = blockIdx.x*32, r0 = blockIdx.y*32;
  int tx = threadIdx.x & 31, ty = threadIdx.x >> 5;   // 32 x 8 threads
  #pragma unroll
  for (int i=0;i<4;i++)
    tile[ty + i*8][tx] = src[(size_t)(r0 + ty + i*8)*Cc + c0 + tx];
  __syncthreads();
  #pragma unroll
  for (int i=0;i<4;i++)
    dst[(size_t)(c0 + ty + i*8)*R + r0 + tx] = (bf16)tile[tx][ty + i*8];
}

// ---------------- positional softmax: pos[h][n][m'] (PERMUTED cols) bf16 ----------------
// Column permutation matches k_attn_pv's S^T lane layout: slot idx = q*144 + T*4 + i
// holds softmax value of original key m = T*16 + q*4 + i. Writes are coalesced by
// computing the INVERSE permutation per contiguous output slot.
__global__ __launch_bounds__(256) void k_pos(const float* __restrict__ w_pos, bf16* __restrict__ pos){
  int t = threadIdx.x, wv = t>>6, lane = t&63;
  int rowid = blockIdx.x*4 + wv;           // [0, H*N)
  int h = rowid / NN, n = rowid % NN;
  float w0 = w_pos[h], w1 = w_pos[HH + h], w2 = w_pos[2*HH + h];
  int nx = n % 24, ny = n / 24;
  float e[9]; float mx = -1e30f;
  #pragma unroll
  for (int j=0;j<9;j++){
    int idx = lane + 64*j;                 // permuted output slot
    int qq = idx / 144;
    int r  = idx - qq*144;
    int m  = (r>>2)*16 + qq*4 + (r&3);     // original key column
    float dx = (float)(m % 24 - nx);
    float dy = (float)(m / 24 - ny);
    float l = dx*w0 + dy*w1 + (dx*dx + dy*dy)*w2;   // b_pos cancels in softmax
    e[j] = l; mx = fmaxf(mx, l);
  }
  #pragma unroll
  for (int s=1;s<64;s<<=1) mx = fmaxf(mx, __shfl_xor(mx, s, 64));
  float sum = 0.f;
  #pragma unroll
  for (int j=0;j<9;j++){ e[j] = __expf(e[j]-mx); sum += e[j]; }
  #pragma unroll
  for (int s=1;s<64;s<<=1) sum += __shfl_xor(sum, s, 64);
  float inv = 1.f/sum;
  bf16* dst = pos + (size_t)rowid*NN;
  #pragma unroll
  for (int j=0;j<9;j++) dst[lane + 64*j] = (bf16)(e[j]*inv);   // coalesced
}

// ---------------- 128x128-tile MFMA mainloop (m97 structure) ----------------
__device__ __forceinline__ void gemm128_main(
    const bf16* __restrict__ A, const bf16* __restrict__ B,
    int lda, int ldb, int K, bf16* As, bf16* Bs, floatx4 (*acc)[4])
{
  int t = threadIdx.x;
  int w = t>>6, m16 = t&15, q = (t&63)>>4;
  int wr = (w>>1)*64, wc = (w&1)*64;
  int sr = t>>2, kg = (t&3)*8;           // staging: slot t -> row t>>2, k-group t&3
  bf16* ldsA = As + w*512;               // wave-uniform LDS base (64 slots * 8 bf16)
  bf16* ldsB = Bs + w*512;
  for (int k0 = 0; k0 < K; k0 += 32){
    GLOAD_LDS16(A + (size_t)sr*lda      + k0 + kg, ldsA);
    GLOAD_LDS16(A + (size_t)(sr+64)*lda + k0 + kg, ldsA + 2048);
    GLOAD_LDS16(B + (size_t)sr*ldb      + k0 + kg, ldsB);
    GLOAD_LDS16(B + (size_t)(sr+64)*ldb + k0 + kg, ldsB + 2048);
    __syncthreads();
    bf16x8 af[4], bfv[4];
    #pragma unroll
    for (int rt=0;rt<4;rt++) af[rt]  = *(const bf16x8*)&As[(wr + rt*16 + m16)*32 + q*8];
    #pragma unroll
    for (int ct=0;ct<4;ct++) bfv[ct] = *(const bf16x8*)&Bs[(wc + ct*16 + m16)*32 + q*8];
    #pragma unroll
    for (int rt=0;rt<4;rt++)
      #pragma unroll
      for (int ct=0;ct<4;ct++)
        acc[rt][ct] = __builtin_amdgcn_mfma_f32_16x16x32_bf16(af[rt], bfv[ct], acc[rt][ct], 0, 0, 0);
    __syncthreads();
  }
}

// ---------------- GEMM1: x[9216,768] @ wcat[768,2304]; scatter epilogue ----------------
// q gets pre-scaled by Dh^-0.5 = 0.125 so the attn kernel needs no score scaling.
__global__ __launch_bounds__(256) void k_gemm1(
    const bf16* __restrict__ x_bf, const bf16* __restrict__ wcatT,
    bf16* __restrict__ q_bf, bf16* __restrict__ k_bf,
    bf16* __restrict__ vt_bf, float* __restrict__ v_out)
{
  __shared__ bf16 As[128*32];
  __shared__ bf16 Bs[128*32];
  int cb = blockIdx.x % 18, rb = blockIdx.x / 18;
  int rowBase = rb*128, colBase = cb*128;
  floatx4 zero = {0.f,0.f,0.f,0.f};
  floatx4 acc[4][4];
  #pragma unroll
  for (int a=0;a<4;a++)
    #pragma unroll
    for (int b=0;b<4;b++) acc[a][b] = zero;
  gemm128_main(x_bf + (size_t)rowBase*CC, wcatT + (size_t)colBase*CC, CC, CC, CC, As, Bs, acc);
  int t = threadIdx.x;
  int w = t>>6, m16 = t&15, q = (t&63)>>4;
  int wr = (w>>1)*64, wc = (w&1)*64;
  #pragma unroll
  for (int rt=0;rt<4;rt++){
    #pragma unroll
    for (int i=0;i<4;i++){
      int row = rowBase + wr + rt*16 + q*4 + i;
      int b = row / NN, n = row % NN;
      #pragma unroll
      for (int ct=0;ct<4;ct++){
        int col = colBase + wc + ct*16 + m16;
        float val = acc[rt][ct][i];
        if (col < 2*CC){
          int s = col / CC, rem = col % CC;
          int h = rem >> 6, d = rem & 63;
          bf16* dst = s ? k_bf : q_bf;
          float sv = s ? val : val*0.125f;
          dst[(((size_t)(b*HH + h)*NN + n) << 6) + d] = (bf16)sv;
        } else {
          int rem = col - 2*CC;
          int h = rem >> 6, d = rem & 63;
          v_out[(((size_t)(b*HH + h)*NN + n) << 6) + d] = val;       // output tuple elem 2
          vt_bf[((size_t)(b*HH + h)*DH + d)*NN + n] = (bf16)val;     // V^T for fused PV
        }
      }
    }
  }
}

// ------- fused attention, 64 q-rows/block, SWAPPED-OPERAND QK^T (S^T in regs):
//         lane owns ONE query (col=m16), keys are q*4+i+T*16 -> 4-contiguous per acc.
//         softmax reductions are scalar + 2 shuffles; blend/attn/P all vectorized. -------
// LDS: K chunk staged (swizzled) in first 8 KB; after scores, same region becomes P[64][600] bf16.
__global__ __launch_bounds__(256, 2) void k_attn_pv(
    const bf16* __restrict__ q_bf, const bf16* __restrict__ k_bf,
    const bf16* __restrict__ vt_bf,
    const bf16* __restrict__ pos, const float* __restrict__ gating,
    float* __restrict__ attn_out, bf16* __restrict__ out1_bf)
{
  __shared__ __align__(16) char smem[64*1200];   // P[64][600] bf16; Ks aliased at offset 0
  int qt = blockIdx.x % 9, bh = blockIdx.x / 9;
  int b = bh / HH, h = bh % HH;
  int n0 = qt*64;
  int t = threadIdx.x;
  int wv = t>>6, m16 = t&15, q = (t&63)>>4;

  // Q frags (B-operand now): loaded once (q pre-scaled by 0.125 in gemm1)
  const bf16* qrow = q_bf + ((size_t)bh*NN + n0 + wv*16 + m16)*DH;
  bf16x8 afr0 = *(const bf16x8*)&qrow[q*8];
  bf16x8 afr1 = *(const bf16x8*)&qrow[32 + q*8];

  const bf16* Kg = k_bf + (size_t)bh*NN*DH;
  floatx4 acc[36];
  #pragma unroll
  for (int T=0;T<36;T++) acc[T] = (floatx4){0.f,0.f,0.f,0.f};

  // staging source with XOR-16B swizzle (dest is forced lane-linear by global_load_lds)
  int key0 = t>>3, g16 = (t&7) ^ (key0 & 7);
  #pragma unroll
  for (int kt=0; kt<9; kt++){
    __syncthreads();
    const bf16* src0 = Kg + (size_t)(kt*64 + key0)*DH + g16*8;
    GLOAD_LDS16(src0,           smem + wv*1024);
    GLOAD_LDS16(src0 + 32*DH,   smem + 4096 + wv*1024);
    __syncthreads();
    #pragma unroll
    for (int ct=0; ct<4; ct++){
      int key = ct*16 + m16;
      int swz = key & 7;
      bf16x8 k0 = *(const bf16x8*)(smem + key*128 + ((q ^ swz)<<4));
      bf16x8 k1 = *(const bf16x8*)(smem + key*128 + (((4 + q) ^ swz)<<4));
      // SWAPPED: A = K-tile (rows=keys), B = Q (cols=queries) -> C = S^T
      acc[kt*4+ct] = __builtin_amdgcn_mfma_f32_16x16x32_bf16(k0, afr0, acc[kt*4+ct], 0, 0, 0);
      acc[kt*4+ct] = __builtin_amdgcn_mfma_f32_16x16x32_bf16(k1, afr1, acc[kt*4+ct], 0, 0, 0);
    }
  }

  // ---- softmax over 576 keys; per lane all 144 values belong to query m16 ----
  float mx = -1e30f;
  #pragma unroll
  for (int T=0;T<36;T++)
    #pragma unroll
    for (int i=0;i<4;i++) mx = fmaxf(mx, acc[T][i]);
  mx = fmaxf(mx, __shfl_xor(mx, 16, 64));
  mx = fmaxf(mx, __shfl_xor(mx, 32, 64));
  float ps = 0.f;
  #pragma unroll
  for (int T=0;T<36;T++)
    #pragma unroll
    for (int i=0;i<4;i++){ float e = __expf(acc[T][i]-mx); acc[T][i]=e; ps += e; }
  ps += __shfl_xor(ps, 16, 64);
  ps += __shfl_xor(ps, 32, 64);

  float g = 1.f/(1.f + __expf(-gating[h]));
  float ig = (1.f-g)/ps, bs = 0.f;

  // blend with positional softmax: permuted layout -> lane's 144 values contiguous
  const bf16* posrow = pos + ((size_t)h*NN + n0 + wv*16 + m16)*NN + q*144;
  #pragma unroll
  for (int T2=0;T2<18;T2++){
    bf16x8 pv = *(const bf16x8*)&posrow[T2*8];
    #pragma unroll
    for (int u=0;u<2;u++)
      #pragma unroll
      for (int i=0;i<4;i++){
        float a = ig*acc[T2*2+u][i] + g*(float)pv[u*4+i];
        acc[T2*2+u][i] = a; bs += a;
      }
  }
  bs += __shfl_xor(bs, 16, 64);
  bs += __shfl_xor(bs, 32, 64);
  float inv = 1.f/bs;

  __syncthreads();   // all K-chunk LDS reads done: P may overwrite the Ks region
  // attn write (float4 per T) + P write (bf16x4 per T into LDS, pitch 1200 B)
  float* arow = attn_out + ((size_t)bh*NN + n0 + wv*16 + m16)*NN + q*4;
  char* prow = smem + (size_t)(wv*16 + m16)*1200 + q*8;
  #pragma unroll
  for (int T=0;T<36;T++){
    float4 o; bf16x4 pb;
    o.x = acc[T][0]*inv; o.y = acc[T][1]*inv; o.z = acc[T][2]*inv; o.w = acc[T][3]*inv;
    pb[0]=(bf16)o.x; pb[1]=(bf16)o.y; pb[2]=(bf16)o.z; pb[3]=(bf16)o.w;
    *(float4*)(arow + (size_t)T*16) = o;
    *(bf16x4*)(prow + T*32) = pb;
  }
  __syncthreads();

  // PV: O[64,64] = P[64,576] @ V[576,64]; each wave owns its 16 rows (A from own LDS strip),
  // B-frags straight from vt (L2-hot, shared across the 9 blocks of this bh)
  floatx4 pacc[4];
  #pragma unroll
  for (int ct=0;ct<4;ct++) pacc[ct] = (floatx4){0.f,0.f,0.f,0.f};
  const char* pbase = smem + (size_t)(wv*16 + m16)*1200 + q*16;
  const bf16* vbase = vt_bf + (size_t)bh*DH*NN + q*8;
  #pragma unroll
  for (int c=0;c<18;c++){
    bf16x8 afr = *(const bf16x8*)(pbase + c*64);
    #pragma unroll
    for (int ct=0;ct<4;ct++){
      bf16x8 bfr = *(const bf16x8*)&vbase[(size_t)(ct*16+m16)*NN + c*32];
      pacc[ct] = __builtin_amdgcn_mfma_f32_16x16x32_bf16(afr, bfr, pacc[ct], 0, 0, 0);
    }
  }
  int rowq = n0 + wv*16 + q*4;
  bf16* obase = out1_bf + ((size_t)(b*NN + rowq))*CC + h*DH + m16;
  #pragma unroll
  for (int ct=0;ct<4;ct++)
    #pragma unroll
    for (int i=0;i<4;i++)
      obase[(size_t)i*CC + ct*16] = (bf16)pacc[ct][i];
}

// ---------------- projection: out = out1 @ w_proj + b_proj ----------------
__global__ __launch_bounds__(256) void k_proj(
    const bf16* __restrict__ out1_bf, const bf16* __restrict__ wprojT,
    const float* __restrict__ b_proj, float* __restrict__ out)
{
  __shared__ bf16 As[128*32];
  __shared__ bf16 Bs[128*32];
  int cb = blockIdx.x % 6, rb = blockIdx.x / 6;
  int rowBase = rb*128, colBase = cb*128;
  floatx4 zero = {0.f,0.f,0.f,0.f};
  floatx4 acc[4][4];
  #pragma unroll
  for (int a=0;a<4;a++)
    #pragma unroll
    for (int b=0;b<4;b++) acc[a][b] = zero;
  gemm128_main(out1_bf + (size_t)rowBase*CC, wprojT + (size_t)colBase*CC, CC, CC, CC, As, Bs, acc);
  int t = threadIdx.x;
  int w = t>>6, m16 = t&15, q = (t&63)>>4;
  int wr = (w>>1)*64, wc = (w&1)*64;
  #pragma unroll
  for (int rt=0;rt<4;rt++){
    #pragma unroll
    for (int i=0;i<4;i++){
      int row = rowBase + wr + rt*16 + q*4 + i;
      #pragma unroll
      for (int ct=0;ct<4;ct++){
        int col = colBase + wc + ct*16 + m16;
        out[(size_t)row*CC + col] = acc[rt][ct][i] + b_proj[col];
      }
    }
  }
}

extern "C" void kernel_launch(void* const* d_in, const int* in_sizes, int n_in,
                              void* d_out, int out_size, void* d_ws, size_t ws_size,
                              hipStream_t stream)
{
  (void)in_sizes; (void)n_in; (void)out_size; (void)ws_size;
  const float* x      = (const float*)d_in[0];
  const float* w_qk   = (const float*)d_in[1];
  const float* w_v    = (const float*)d_in[2];
  const float* w_proj = (const float*)d_in[3];
  const float* b_proj = (const float*)d_in[4];
  const float* w_pos  = (const float*)d_in[5];
  // d_in[6] = b_pos: cancels in softmax, unused
  const float* gating = (const float*)d_in[7];

  float* out_ptr  = (float*)d_out;
  float* attn_ptr = out_ptr + (size_t)BB*NN*CC;        // 7,077,888
  float* v_ptr    = attn_ptr + (size_t)BB*HH*NN*NN;    // +63,700,992

  char* w = (char*)d_ws;
  bf16* x_bf    = (bf16*)(w);                 // 14,155,776 B  (reused as out1_bf)
  bf16* wcatT   = (bf16*)(w + 14155776);      //  3,538,944 B  [2304][768]
  bf16* wprojT  = (bf16*)(w + 17694720);      //  1,179,648 B  [768][768]
  bf16* q_bf    = (bf16*)(w + 18874368);      // 14,155,776 B  [B,H,N,64]  (pre-scaled by 0.125)
  bf16* k_bf    = (bf16*)(w + 33030144);      // 14,155,776 B  [B,H,N,64]
  bf16* vt_bf   = (bf16*)(w + 47185920);      // 14,155,776 B  [B,H,64,N]
  bf16* pos_bf  = (bf16*)(w + 61341696);      //  7,962,624 B  [H,N,N] bf16 (col-permuted)
  bf16* out1_bf = x_bf;                       // alias: x_bf dead after k_gemm1

  k_convert<<<6912, 256, 0, stream>>>(x, x_bf, (BB*NN*CC)/4);
  k_transpose<<<dim3(48,24), 256, 0, stream>>>(w_qk, wcatT, CC, 2*CC);
  k_transpose<<<dim3(24,24), 256, 0, stream>>>(w_v, wcatT + (size_t)2*CC*CC, CC, CC);
  k_transpose<<<dim3(24,24), 256, 0, stream>>>(w_proj, wprojT, CC, CC);
  k_pos<<<(HH*NN)/4, 256, 0, stream>>>(w_pos, pos_bf);
  k_gemm1<<<72*18, 256, 0, stream>>>(x_bf, wcatT, q_bf, k_bf, vt_bf, v_ptr);
  k_attn_pv<<<192*9, 256, 0, stream>>>(q_bf, k_bf, vt_bf, pos_bf, gating, attn_ptr, out1_bf);
  k_proj<<<72*6, 256, 0, stream>>>(out1_bf, wprojT, b_proj, out_ptr);
}

// Round 2
// 520.743 us; speedup vs baseline: 1.0438x; 1.0438x over previous
//
#include <hip/hip_runtime.h>
#include <hip/hip_bf16.h>

typedef __bf16 bf16;
typedef __attribute__((ext_vector_type(4))) __bf16 bf16x4;
typedef __attribute__((ext_vector_type(8))) __bf16 bf16x8;
typedef __attribute__((ext_vector_type(4))) float floatx4;

#define BB 16
#define NN 576
#define CC 768
#define HH 12
#define DH 64

// async global->LDS, 16B per lane; LDS dest = wave-uniform base + lane*16
#define GLOAD_LDS16(gp, lp) __builtin_amdgcn_global_load_lds( \
    (const __attribute__((address_space(1))) unsigned int*)(const void*)(gp), \
    (__attribute__((address_space(3))) unsigned int*)(void*)(lp), 16, 0, 0)

// ---------------- convert fp32 -> bf16 (vectorized x4) ----------------
__global__ void k_convert(const float* __restrict__ in, bf16* __restrict__ out, int n4){
  int i = blockIdx.x*blockDim.x + threadIdx.x;
  if (i < n4){
    float4 f = ((const float4*)in)[i];
    bf16x4 o;
    o[0]=(bf16)f.x; o[1]=(bf16)f.y; o[2]=(bf16)f.z; o[3]=(bf16)f.w;
    ((bf16x4*)out)[i] = o;
  }
}

// ---------------- tiled transpose fp32[R][Cc] -> bf16[Cc][R] ----------------
__global__ void k_transpose(const float* __restrict__ src, bf16* __restrict__ dst, int R, int Cc){
  __shared__ float tile[32][33];
  int c0 = blockIdx.x*32, r0 = blockIdx.y*32;
  int tx = threadIdx.x & 31, ty = threadIdx.x >> 5;   // 32 x 8 threads
  #pragma unroll
  for (int i=0;i<4;i++)
    tile[ty + i*8][tx] = src[(size_t)(r0 + ty + i*8)*Cc + c0 + tx];
  __syncthreads();
  #pragma unroll
  for (int i=0;i<4;i++)
    dst[(size_t)(c0 + ty + i*8)*R + r0 + tx] = (bf16)tile[tx][ty + i*8];
}

// ---------------- positional softmax: pos[h][n][m'] (PERMUTED cols) bf16 ----------------
// Column permutation matches k_attn_pv's S^T lane layout: slot idx = q*144 + T*4 + i
// holds softmax value of original key m = T*16 + q*4 + i.
__global__ __launch_bounds__(256) void k_pos(const float* __restrict__ w_pos, bf16* __restrict__ pos){
  int t = threadIdx.x, wv = t>>6, lane = t&63;
  int rowid = blockIdx.x*4 + wv;           // [0, H*N)
  int h = rowid / NN, n = rowid % NN;
  float w0 = w_pos[h], w1 = w_pos[HH + h], w2 = w_pos[2*HH + h];
  int nx = n % 24, ny = n / 24;
  float e[9]; float mx = -1e30f;
  #pragma unroll
  for (int j=0;j<9;j++){
    int idx = lane + 64*j;                 // permuted output slot
    int qq = idx / 144;
    int r  = idx - qq*144;
    int m  = (r>>2)*16 + qq*4 + (r&3);     // original key column
    float dx = (float)(m % 24 - nx);
    float dy = (float)(m / 24 - ny);
    float l = dx*w0 + dy*w1 + (dx*dx + dy*dy)*w2;   // b_pos cancels in softmax
    e[j] = l; mx = fmaxf(mx, l);
  }
  #pragma unroll
  for (int s=1;s<64;s<<=1) mx = fmaxf(mx, __shfl_xor(mx, s, 64));
  float sum = 0.f;
  #pragma unroll
  for (int j=0;j<9;j++){ e[j] = __expf(e[j]-mx); sum += e[j]; }
  #pragma unroll
  for (int s=1;s<64;s<<=1) sum += __shfl_xor(sum, s, 64);
  float inv = 1.f/sum;
  bf16* dst = pos + (size_t)rowid*NN;
  #pragma unroll
  for (int j=0;j<9;j++) dst[lane + 64*j] = (bf16)(e[j]*inv);   // coalesced
}

// ---------------- 128x128-tile MFMA mainloop (m97 structure) ----------------
__device__ __forceinline__ void gemm128_main(
    const bf16* __restrict__ A, const bf16* __restrict__ B,
    int lda, int ldb, int K, bf16* As, bf16* Bs, floatx4 (*acc)[4])
{
  int t = threadIdx.x;
  int w = t>>6, m16 = t&15, q = (t&63)>>4;
  int wr = (w>>1)*64, wc = (w&1)*64;
  int sr = t>>2, kg = (t&3)*8;           // staging: slot t -> row t>>2, k-group t&3
  bf16* ldsA = As + w*512;               // wave-uniform LDS base (64 slots * 8 bf16)
  bf16* ldsB = Bs + w*512;
  for (int k0 = 0; k0 < K; k0 += 32){
    GLOAD_LDS16(A + (size_t)sr*lda      + k0 + kg, ldsA);
    GLOAD_LDS16(A + (size_t)(sr+64)*lda + k0 + kg, ldsA + 2048);
    GLOAD_LDS16(B + (size_t)sr*ldb      + k0 + kg, ldsB);
    GLOAD_LDS16(B + (size_t)(sr+64)*ldb + k0 + kg, ldsB + 2048);
    __syncthreads();
    bf16x8 af[4], bfv[4];
    #pragma unroll
    for (int rt=0;rt<4;rt++) af[rt]  = *(const bf16x8*)&As[(wr + rt*16 + m16)*32 + q*8];
    #pragma unroll
    for (int ct=0;ct<4;ct++) bfv[ct] = *(const bf16x8*)&Bs[(wc + ct*16 + m16)*32 + q*8];
    #pragma unroll
    for (int rt=0;rt<4;rt++)
      #pragma unroll
      for (int ct=0;ct<4;ct++)
        acc[rt][ct] = __builtin_amdgcn_mfma_f32_16x16x32_bf16(af[rt], bfv[ct], acc[rt][ct], 0, 0, 0);
    __syncthreads();
  }
}

// ---------------- GEMM1: x[9216,768] @ wcat[768,2304]; scatter epilogue ----------------
// q gets pre-scaled by Dh^-0.5 = 0.125 so the attn kernel needs no score scaling.
__global__ __launch_bounds__(256) void k_gemm1(
    const bf16* __restrict__ x_bf, const bf16* __restrict__ wcatT,
    bf16* __restrict__ q_bf, bf16* __restrict__ k_bf,
    bf16* __restrict__ vt_bf, float* __restrict__ v_out)
{
  __shared__ bf16 As[128*32];
  __shared__ bf16 Bs[128*32];
  int cb = blockIdx.x % 18, rb = blockIdx.x / 18;
  int rowBase = rb*128, colBase = cb*128;
  floatx4 zero = {0.f,0.f,0.f,0.f};
  floatx4 acc[4][4];
  #pragma unroll
  for (int a=0;a<4;a++)
    #pragma unroll
    for (int b=0;b<4;b++) acc[a][b] = zero;
  gemm128_main(x_bf + (size_t)rowBase*CC, wcatT + (size_t)colBase*CC, CC, CC, CC, As, Bs, acc);
  int t = threadIdx.x;
  int w = t>>6, m16 = t&15, q = (t&63)>>4;
  int wr = (w>>1)*64, wc = (w&1)*64;
  #pragma unroll
  for (int rt=0;rt<4;rt++){
    #pragma unroll
    for (int i=0;i<4;i++){
      int row = rowBase + wr + rt*16 + q*4 + i;
      int b = row / NN, n = row % NN;
      #pragma unroll
      for (int ct=0;ct<4;ct++){
        int col = colBase + wc + ct*16 + m16;
        float val = acc[rt][ct][i];
        if (col < 2*CC){
          int s = col / CC, rem = col % CC;
          int h = rem >> 6, d = rem & 63;
          bf16* dst = s ? k_bf : q_bf;
          float sv = s ? val : val*0.125f;
          dst[(((size_t)(b*HH + h)*NN + n) << 6) + d] = (bf16)sv;
        } else {
          int rem = col - 2*CC;
          int h = rem >> 6, d = rem & 63;
          v_out[(((size_t)(b*HH + h)*NN + n) << 6) + d] = val;       // output tuple elem 2
          vt_bf[((size_t)(b*HH + h)*DH + d)*NN + n] = (bf16)val;     // V^T for fused PV
        }
      }
    }
  }
}

// ------- fused attention, 64 q-rows/block, SWAPPED-OPERAND QK^T (S^T in regs).
//   Round-2 restructure:
//   (1) SINGLE-STAGE K: all 18 global_load_lds rounds issued back-to-back (MLP=18),
//       ONE barrier drain instead of 9 (removes 16 barriers + 8 latency exposures).
//   (2) PV wave-owns-COLUMNS: V tile read once per block (was 4x redundant). -------
// LDS: K[576][128B] swizzled in first 73728 B; after scores, region becomes P[64][600] bf16.
__global__ __launch_bounds__(256, 2) void k_attn_pv(
    const bf16* __restrict__ q_bf, const bf16* __restrict__ k_bf,
    const bf16* __restrict__ vt_bf,
    const bf16* __restrict__ pos, const float* __restrict__ gating,
    float* __restrict__ attn_out, bf16* __restrict__ out1_bf)
{
  __shared__ __align__(16) char smem[64*1200];   // P[64][600] bf16; K staged at offset 0
  int qt = blockIdx.x % 9, bh = blockIdx.x / 9;
  int b = bh / HH, h = bh % HH;
  int n0 = qt*64;
  int t = threadIdx.x;
  int wv = t>>6, m16 = t&15, q = (t&63)>>4;

  // ---- stage ALL of K (576 rows x 128 B = 73728 B), XOR-16B source swizzle ----
  // LDS[row][g] = K[row][g ^ (row&7)] ; round r stages rows r*32 .. r*32+31.
  int key0 = t>>3, g16 = (t&7) ^ (key0 & 7);
  const bf16* Kg = k_bf + (size_t)bh*NN*DH;
  const bf16* ksrc = Kg + (size_t)key0*DH + g16*8;
  char* kdst = smem + wv*1024;        // wave-uniform base; HW adds lane*16
  #pragma unroll
  for (int r=0;r<18;r++)
    GLOAD_LDS16(ksrc + (size_t)(r*32)*DH, kdst + r*4096);

  // Q frags (B-operand) load while K streams (q pre-scaled by 0.125 in gemm1)
  const bf16* qrow = q_bf + ((size_t)bh*NN + n0 + wv*16 + m16)*DH;
  bf16x8 qf0 = *(const bf16x8*)&qrow[q*8];
  bf16x8 qf1 = *(const bf16x8*)&qrow[32 + q*8];
  float gh = gating[h];

  floatx4 acc[36];
  #pragma unroll
  for (int T=0;T<36;T++) acc[T] = (floatx4){0.f,0.f,0.f,0.f};

  __syncthreads();   // single vmcnt drain: all of K resident

  #pragma unroll
  for (int kt=0; kt<9; kt++){
    #pragma unroll
    for (int ct=0; ct<4; ct++){
      int key = kt*64 + ct*16 + m16;
      int swz = key & 7;
      const char* kb = smem + (size_t)key*128;
      bf16x8 k0 = *(const bf16x8*)(kb + ((q ^ swz)<<4));
      bf16x8 k1 = *(const bf16x8*)(kb + (((4 + q) ^ swz)<<4));
      // SWAPPED: A = K-tile (rows=keys), B = Q (cols=queries) -> C = S^T
      acc[kt*4+ct] = __builtin_amdgcn_mfma_f32_16x16x32_bf16(k0, qf0, acc[kt*4+ct], 0, 0, 0);
      acc[kt*4+ct] = __builtin_amdgcn_mfma_f32_16x16x32_bf16(k1, qf1, acc[kt*4+ct], 0, 0, 0);
    }
  }

  // ---- softmax over 576 keys; per lane all 144 values belong to query m16 ----
  float mx = -1e30f;
  #pragma unroll
  for (int T=0;T<36;T++)
    #pragma unroll
    for (int i=0;i<4;i++) mx = fmaxf(mx, acc[T][i]);
  mx = fmaxf(mx, __shfl_xor(mx, 16, 64));
  mx = fmaxf(mx, __shfl_xor(mx, 32, 64));
  float ps = 0.f;
  #pragma unroll
  for (int T=0;T<36;T++)
    #pragma unroll
    for (int i=0;i<4;i++){ float e = __expf(acc[T][i]-mx); acc[T][i]=e; ps += e; }
  ps += __shfl_xor(ps, 16, 64);
  ps += __shfl_xor(ps, 32, 64);

  float g = 1.f/(1.f + __expf(-gh));
  float ig = (1.f-g)/ps, bs = 0.f;

  // blend with positional softmax: permuted layout -> lane's 144 values contiguous
  const bf16* posrow = pos + ((size_t)h*NN + n0 + wv*16 + m16)*NN + q*144;
  #pragma unroll
  for (int T2=0;T2<18;T2++){
    bf16x8 pv = *(const bf16x8*)&posrow[T2*8];
    #pragma unroll
    for (int u=0;u<2;u++)
      #pragma unroll
      for (int i=0;i<4;i++){
        float a = ig*acc[T2*2+u][i] + g*(float)pv[u*4+i];
        acc[T2*2+u][i] = a; bs += a;
      }
  }
  bs += __shfl_xor(bs, 16, 64);
  bs += __shfl_xor(bs, 32, 64);
  float inv = 1.f/bs;

  __syncthreads();   // all K LDS reads done: P may overwrite the K region
  // attn write (float4 per T) + P write (bf16x4 per T into LDS, pitch 1200 B)
  float* arow = attn_out + ((size_t)bh*NN + n0 + wv*16 + m16)*NN + q*4;
  char* prow = smem + (size_t)(wv*16 + m16)*1200 + q*8;
  #pragma unroll
  for (int T=0;T<36;T++){
    float4 o; bf16x4 pb;
    o.x = acc[T][0]*inv; o.y = acc[T][1]*inv; o.z = acc[T][2]*inv; o.w = acc[T][3]*inv;
    pb[0]=(bf16)o.x; pb[1]=(bf16)o.y; pb[2]=(bf16)o.z; pb[3]=(bf16)o.w;
    *(float4*)(arow + (size_t)T*16) = o;
    *(bf16x4*)(prow + T*32) = pb;
  }
  __syncthreads();

  // PV: O[64,64] = P[64,576] @ V[576,64]; wave wv owns COLUMN block wv*16..+15,
  // so the V tile is read exactly once per block (B-frags from vt, L2-hot);
  // A-frags (P rows) come from shared LDS.
  floatx4 pacc[4];
  #pragma unroll
  for (int rt=0;rt<4;rt++) pacc[rt] = (floatx4){0.f,0.f,0.f,0.f};
  const bf16* vb = vt_bf + (size_t)bh*DH*NN + (size_t)(wv*16 + m16)*NN + q*8;
  #pragma unroll
  for (int c=0;c<18;c++){
    bf16x8 bfr = *(const bf16x8*)&vb[c*32];
    #pragma unroll
    for (int rt=0;rt<4;rt++){
      bf16x8 afr = *(const bf16x8*)(smem + (size_t)(rt*16 + m16)*1200 + q*16 + c*64);
      pacc[rt] = __builtin_amdgcn_mfma_f32_16x16x32_bf16(afr, bfr, pacc[rt], 0, 0, 0);
    }
  }
  // C layout: row = rt*16 + q*4 + i, col = wv*16 + m16
  bf16* ob = out1_bf + ((size_t)(b*NN + n0))*CC + h*DH + wv*16 + m16;
  #pragma unroll
  for (int rt=0;rt<4;rt++)
    #pragma unroll
    for (int i=0;i<4;i++)
      ob[(size_t)(rt*16 + q*4 + i)*CC] = (bf16)pacc[rt][i];
}

// ---------------- projection: out = out1 @ w_proj + b_proj ----------------
__global__ __launch_bounds__(256) void k_proj(
    const bf16* __restrict__ out1_bf, const bf16* __restrict__ wprojT,
    const float* __restrict__ b_proj, float* __restrict__ out)
{
  __shared__ bf16 As[128*32];
  __shared__ bf16 Bs[128*32];
  int cb = blockIdx.x % 6, rb = blockIdx.x / 6;
  int rowBase = rb*128, colBase = cb*128;
  floatx4 zero = {0.f,0.f,0.f,0.f};
  floatx4 acc[4][4];
  #pragma unroll
  for (int a=0;a<4;a++)
    #pragma unroll
    for (int b=0;b<4;b++) acc[a][b] = zero;
  gemm128_main(out1_bf + (size_t)rowBase*CC, wprojT + (size_t)colBase*CC, CC, CC, CC, As, Bs, acc);
  int t = threadIdx.x;
  int w = t>>6, m16 = t&15, q = (t&63)>>4;
  int wr = (w>>1)*64, wc = (w&1)*64;
  #pragma unroll
  for (int rt=0;rt<4;rt++){
    #pragma unroll
    for (int i=0;i<4;i++){
      int row = rowBase + wr + rt*16 + q*4 + i;
      #pragma unroll
      for (int ct=0;ct<4;ct++){
        int col = colBase + wc + ct*16 + m16;
        out[(size_t)row*CC + col] = acc[rt][ct][i] + b_proj[col];
      }
    }
  }
}

extern "C" void kernel_launch(void* const* d_in, const int* in_sizes, int n_in,
                              void* d_out, int out_size, void* d_ws, size_t ws_size,
                              hipStream_t stream)
{
  (void)in_sizes; (void)n_in; (void)out_size; (void)ws_size;
  const float* x      = (const float*)d_in[0];
  const float* w_qk   = (const float*)d_in[1];
  const float* w_v    = (const float*)d_in[2];
  const float* w_proj = (const float*)d_in[3];
  const float* b_proj = (const float*)d_in[4];
  const float* w_pos  = (const float*)d_in[5];
  // d_in[6] = b_pos: cancels in softmax, unused
  const float* gating = (const float*)d_in[7];

  float* out_ptr  = (float*)d_out;
  float* attn_ptr = out_ptr + (size_t)BB*NN*CC;        // 7,077,888
  float* v_ptr    = attn_ptr + (size_t)BB*HH*NN*NN;    // +63,700,992

  char* w = (char*)d_ws;
  bf16* x_bf    = (bf16*)(w);                 // 14,155,776 B  (reused as out1_bf)
  bf16* wcatT   = (bf16*)(w + 14155776);      //  3,538,944 B  [2304][768]
  bf16* wprojT  = (bf16*)(w + 17694720);      //  1,179,648 B  [768][768]
  bf16* q_bf    = (bf16*)(w + 18874368);      // 14,155,776 B  [B,H,N,64]  (pre-scaled by 0.125)
  bf16* k_bf    = (bf16*)(w + 33030144);      // 14,155,776 B  [B,H,N,64]
  bf16* vt_bf   = (bf16*)(w + 47185920);      // 14,155,776 B  [B,H,64,N]
  bf16* pos_bf  = (bf16*)(w + 61341696);      //  7,962,624 B  [H,N,N] bf16 (col-permuted)
  bf16* out1_bf = x_bf;                       // alias: x_bf dead after k_gemm1

  k_convert<<<6912, 256, 0, stream>>>(x, x_bf, (BB*NN*CC)/4);
  k_transpose<<<dim3(48,24), 256, 0, stream>>>(w_qk, wcatT, CC, 2*CC);
  k_transpose<<<dim3(24,24), 256, 0, stream>>>(w_v, wcatT + (size_t)2*CC*CC, CC, CC);
  k_transpose<<<dim3(24,24), 256, 0, stream>>>(w_proj, wprojT, CC, CC);
  k_pos<<<(HH*NN)/4, 256, 0, stream>>>(w_pos, pos_bf);
  k_gemm1<<<72*18, 256, 0, stream>>>(x_bf, wcatT, q_bf, k_bf, vt_bf, v_ptr);
  k_attn_pv<<<192*9, 256, 0, stream>>>(q_bf, k_bf, vt_bf, pos_bf, gating, attn_ptr, out1_bf);
  k_proj<<<72*6, 256, 0, stream>>>(out1_bf, wprojT, b_proj, out_ptr);
}